// Round 2
// baseline (156.752 us; speedup 1.0000x reference)
//
#include <hip/hip_runtime.h>

typedef _Float16 half8_t __attribute__((ext_vector_type(8)));
typedef _Float16 half4_t __attribute__((ext_vector_type(4)));
typedef _Float16 half2_t __attribute__((ext_vector_type(2)));
typedef __fp16 fp16x2 __attribute__((ext_vector_type(2)));
typedef float f32x4 __attribute__((ext_vector_type(4)));

#define S_LEN 2048
#define D_DIM 64
#define SD (S_LEN * D_DIM)
#define BC 64
#define NKT (S_LEN / BC)   // 32 key tiles
#define LDK 72             // f16 row stride (64 + 8 pad)
#define LDO 68             // f32 row stride for epilogue

// 512 threads = 8 waves; wave w owns q rows [16w,16w+16).
// KEY CHANGE vs prior round: P never touches LDS. The 16x16x32 QK output
// (lane g,c holds S[q=c][k=16mt+4g+r]) is EXACTLY the B-fragment of
// v_mfma_f32_16x16x16f16 (B[k=4g+e][col=c]), so softmaxed p-values pack
// in-register (cvt_pkrtz, already needed) and feed PV directly as 4 K=16
// MFMA steps. Removes 4 ds_write_b64 + 2 ds_read_b128 + a full LDS
// write->read latency from every iteration's critical path, and frees
// 18KB LDS (63488 -> 45056). Prior round proved occupancy is NOT the
// limiter (2x waves, zero speedup): the LDS pipe + lockstep per-iter
// dependency chain is. Double-buffered K/V, one barrier/iter, register
// prefetch one tile ahead, additive f32 mask, exact defer-rescale.
__global__ __launch_bounds__(512, 4)
void fattn_kernel(const float* __restrict__ Qg, const float* __restrict__ Kg,
                  const float* __restrict__ Vg, const int* __restrict__ Mg,
                  float* __restrict__ Og) {
  __shared__ __align__(16) char smem[45056];
  // K buf0 [0,9216) K buf1 [9216,18432) V buf0 [18432,27648) V buf1 [27648,36864)
  float* Msh = (float*)(smem + 36864);  // [2048] additive mask {0,-1e30}
  float* Osh = (float*)smem;            // [128][68] f32, epilogue reuse

  const int t = threadIdx.x;
  const int w = t >> 6;
  const int lane = t & 63;
  const int g = lane >> 4;   // quad
  const int c = lane & 15;

  // bh in low bits: all 16 q-blocks of one (b,h) hit the SAME XCD
  const int bh = blockIdx.x & 31;
  const int qt = blockIdx.x >> 5;
  const int qb = qt * 128;

  const float* Qb = Qg + (size_t)bh * SD;
  const float* Kb = Kg + (size_t)bh * SD;
  const float* Vb = Vg + (size_t)bh * SD;
  const int*   Mb = Mg + (size_t)(bh >> 3) * S_LEN;  // H = 8
  float*       Ob = Og + (size_t)bh * SD;

  // ---- stage additive mask -> LDS once: (m-1)*1e30 -> {0, -1e30} ----
  {
    int4 m0 = *(const int4*)(Mb + 4 * t);
    float4 f0;
    f0.x = (float)(m0.x - 1) * 1e30f; f0.y = (float)(m0.y - 1) * 1e30f;
    f0.z = (float)(m0.z - 1) * 1e30f; f0.w = (float)(m0.w - 1) * 1e30f;
    *(float4*)(Msh + 4 * t) = f0;
  }

  // ---- Q^T B-frag for q = qb + 16w + c; fold 1/8 * log2(e) ----
  const float qscale = 0.125f * 1.44269504088896340736f;
  half8_t qf[2];
  {
    const float* qp = Qb + (size_t)(qb + 16 * w + c) * D_DIM + 8 * g;
#pragma unroll
    for (int ks = 0; ks < 2; ++ks) {
      float4 lo = *(const float4*)(qp + 32 * ks);
      float4 hi = *(const float4*)(qp + 32 * ks + 4);
      fp16x2 p0 = __builtin_amdgcn_cvt_pkrtz(lo.x * qscale, lo.y * qscale);
      fp16x2 p1 = __builtin_amdgcn_cvt_pkrtz(lo.z * qscale, lo.w * qscale);
      fp16x2 p2 = __builtin_amdgcn_cvt_pkrtz(hi.x * qscale, hi.y * qscale);
      fp16x2 p3 = __builtin_amdgcn_cvt_pkrtz(hi.z * qscale, hi.w * qscale);
      half8_t hh;
      hh[0] = (_Float16)p0[0]; hh[1] = (_Float16)p0[1];
      hh[2] = (_Float16)p1[0]; hh[3] = (_Float16)p1[1];
      hh[4] = (_Float16)p2[0]; hh[5] = (_Float16)p2[1];
      hh[6] = (_Float16)p3[0]; hh[7] = (_Float16)p3[1];
      qf[ks] = hh;
    }
  }

  // ---- staging coordinates (512 threads) ----
  const int krow0 = t >> 4;   // 0..31; K row = krow0 + 32*it
  const int kc4   = t & 15;   // K float4 column
  const int vp    = t >> 4;   // V d-pair 0..31
  const int vkpl  = t & 15;   // V key-pair low; kp = vkpl + 16*kc

  float4 kr[2];
  float2 vr[4];
  auto prefetch = [&](int kb2) {
#pragma unroll
    for (int it = 0; it < 2; ++it)
      kr[it] = *(const float4*)(Kb + (size_t)(kb2 + krow0 + 32 * it) * D_DIM + kc4 * 4);
#pragma unroll
    for (int kc = 0; kc < 2; ++kc) {
      const float* vpp = Vb + (size_t)(kb2 + 2 * (vkpl + 16 * kc)) * D_DIM + 2 * vp;
      vr[2 * kc]     = *(const float2*)(vpp);
      vr[2 * kc + 1] = *(const float2*)(vpp + D_DIM);
    }
  };
  auto stage = [&](int buf) {
    _Float16* Kd = (_Float16*)(smem + 9216 * buf);
    _Float16* Vd = (_Float16*)(smem + 18432 + 9216 * buf);
#pragma unroll
    for (int it = 0; it < 2; ++it) {
      fp16x2 a  = __builtin_amdgcn_cvt_pkrtz(kr[it].x, kr[it].y);
      fp16x2 b2 = __builtin_amdgcn_cvt_pkrtz(kr[it].z, kr[it].w);
      half4_t h;
      h[0] = (_Float16)a[0]; h[1] = (_Float16)a[1];
      h[2] = (_Float16)b2[0]; h[3] = (_Float16)b2[1];
      *(half4_t*)(Kd + (krow0 + 32 * it) * LDK + kc4 * 4) = h;
    }
#pragma unroll
    for (int kc = 0; kc < 2; ++kc) {
      int kp = vkpl + 16 * kc;
      fp16x2 h0 = __builtin_amdgcn_cvt_pkrtz(vr[2 * kc].x, vr[2 * kc + 1].x);
      fp16x2 h1 = __builtin_amdgcn_cvt_pkrtz(vr[2 * kc].y, vr[2 * kc + 1].y);
      half2_t g0; g0[0] = (_Float16)h0[0]; g0[1] = (_Float16)h0[1];
      half2_t g1; g1[0] = (_Float16)h1[0]; g1[1] = (_Float16)h1[1];
      *(half2_t*)(Vd + (2 * vp) * LDK + 2 * kp) = g0;
      *(half2_t*)(Vd + (2 * vp + 1) * LDK + 2 * kp) = g1;
    }
  };

  f32x4 acc[4];
#pragma unroll
  for (int i = 0; i < 4; ++i)
#pragma unroll
    for (int j = 0; j < 4; ++j) acc[i][j] = 0.f;
  float mrun = -1e30f;
  float lrun = 0.f;

  // prologue: tile0 -> buf0; tile1 in flight
  prefetch(0);
  stage(0);
  prefetch(BC);
  __syncthreads();

  for (int kt = 0; kt < NKT; ++kt) {
    const int kb = kt * BC;
    const int cur = kt & 1;

    if (kt < NKT - 1) stage(cur ^ 1);
    if (kt < NKT - 2) prefetch(kb + 2 * BC);

    const _Float16* Kc = (const _Float16*)(smem + 9216 * cur);
    const _Float16* Vc = (const _Float16*)(smem + 18432 + 9216 * cur);

    // ---- S^T = K . Q^T ----
    f32x4 sT[4];
#pragma unroll
    for (int mt = 0; mt < 4; ++mt) {
      f32x4 z;
#pragma unroll
      for (int j = 0; j < 4; ++j) z[j] = 0.f;
#pragma unroll
      for (int ks = 0; ks < 2; ++ks) {
        half8_t kf = *(half8_t*)(Kc + (16 * mt + c) * LDK + ks * 32 + 8 * g);
        z = __builtin_amdgcn_mfma_f32_16x16x32_f16(kf, qf[ks], z, 0, 0, 0);
      }
      sT[mt] = z;
    }

    // ---- V A-frags for K=16 PV (b64); issued early so LDS latency hides
    //      under the whole softmax VALU phase ----
    half4_t vf[4][4];  // [d-tile][k-step]
#pragma unroll
    for (int dt = 0; dt < 4; ++dt)
#pragma unroll
      for (int kst = 0; kst < 4; ++kst)
        vf[dt][kst] = *(half4_t*)(Vc + (16 * dt + c) * LDK + 16 * kst + 4 * g);

    // ---- additive mask (broadcast LDS reads) ----
    f32x4 mvf[4];
#pragma unroll
    for (int mt = 0; mt < 4; ++mt)
      mvf[mt] = *(const f32x4*)(Msh + kb + 16 * mt + 4 * g);
#pragma unroll
    for (int mt = 0; mt < 4; ++mt)
#pragma unroll
      for (int r = 0; r < 4; ++r) sT[mt][r] += mvf[mt][r];

    // ---- online softmax (per q = c): tree-max + 2 shfls ----
    float tm[4];
#pragma unroll
    for (int mt = 0; mt < 4; ++mt)
      tm[mt] = fmaxf(fmaxf(sT[mt][0], sT[mt][1]), fmaxf(sT[mt][2], sT[mt][3]));
    float tmax = fmaxf(fmaxf(tm[0], tm[1]), fmaxf(tm[2], tm[3]));
    tmax = fmaxf(tmax, __shfl_xor(tmax, 16));
    tmax = fmaxf(tmax, __shfl_xor(tmax, 32));

    // exact defer-rescale: when no q-row in this wave raises its max,
    // alpha == 1.0 exactly -> skip the acc/lrun scaling pass entirely.
    if (!__all(tmax <= mrun)) {
      float mnew = fmaxf(mrun, tmax);
      float alpha = __builtin_amdgcn_exp2f(mrun - mnew);
      mrun = mnew;
      lrun *= alpha;
#pragma unroll
      for (int mt = 0; mt < 4; ++mt) {
        acc[mt][0] *= alpha; acc[mt][1] *= alpha;
        acc[mt][2] *= alpha; acc[mt][3] *= alpha;
      }
    }

    // ---- exp + in-register pack + PV (K=16 MFMA, B-frag == sT layout) ----
    float lt = 0.f;
#pragma unroll
    for (int mt = 0; mt < 4; ++mt) {
      float pv0 = __builtin_amdgcn_exp2f(sT[mt][0] - mrun);
      float pv1 = __builtin_amdgcn_exp2f(sT[mt][1] - mrun);
      float pv2 = __builtin_amdgcn_exp2f(sT[mt][2] - mrun);
      float pv3 = __builtin_amdgcn_exp2f(sT[mt][3] - mrun);
      lt += (pv0 + pv1) + (pv2 + pv3);
      fp16x2 p01 = __builtin_amdgcn_cvt_pkrtz(pv0, pv1);
      fp16x2 p23 = __builtin_amdgcn_cvt_pkrtz(pv2, pv3);
      half4_t pf;
      pf[0] = (_Float16)p01[0]; pf[1] = (_Float16)p01[1];
      pf[2] = (_Float16)p23[0]; pf[3] = (_Float16)p23[1];
#pragma unroll
      for (int dt = 0; dt < 4; ++dt)
        acc[dt] = __builtin_amdgcn_mfma_f32_16x16x16f16(vf[dt][mt], pf,
                                                        acc[dt], 0, 0, 0);
    }
    lt += __shfl_xor(lt, 16);
    lt += __shfl_xor(lt, 32);
    lrun += lt;

    __syncthreads();  // single barrier: guards next iter's buffer swap
  }

  // ---- epilogue: /l, transpose O^T -> O via LDS, coalesced stores ----
  {
    float linv = 1.f / lrun;
#pragma unroll
    for (int mt = 0; mt < 4; ++mt)
#pragma unroll
      for (int r = 0; r < 4; ++r)
        Osh[(16 * w + c) * LDO + 16 * mt + 4 * g + r] = acc[mt][r] * linv;
  }
  __syncthreads();
  {
    int f8 = t & 7;
#pragma unroll
    for (int i = 0; i < 2; ++i) {
      int q = (t >> 3) + 64 * i;
#pragma unroll
      for (int j = 0; j < 2; ++j) {
        int c4 = f8 + 8 * j;
        f32x4 o = *(f32x4*)(Osh + q * LDO + c4 * 4);
        *(float4*)(Ob + (size_t)(qb + q) * D_DIM + c4 * 4) =
            make_float4(o.x, o.y, o.z, o.w);
      }
    }
  }
}

extern "C" void kernel_launch(void* const* d_in, const int* in_sizes, int n_in,
                              void* d_out, int out_size, void* d_ws, size_t ws_size,
                              hipStream_t stream) {
  (void)in_sizes; (void)n_in; (void)d_ws; (void)ws_size; (void)out_size;
  const float* Q = (const float*)d_in[0];
  const float* K = (const float*)d_in[1];
  const float* V = (const float*)d_in[2];
  const int*   M = (const int*)d_in[3];
  float* O = (float*)d_out;
  // grid: bh fast (XCD locality), 16 q-tiles slow
  fattn_kernel<<<dim3(32 * 16), dim3(512), 0, stream>>>(Q, K, V, M, O);
}

// Round 3
// 153.755 us; speedup vs baseline: 1.0195x; 1.0195x over previous
//
#include <hip/hip_runtime.h>

typedef _Float16 half8_t __attribute__((ext_vector_type(8)));
typedef _Float16 half4_t __attribute__((ext_vector_type(4)));
typedef _Float16 half2_t __attribute__((ext_vector_type(2)));
typedef __fp16 fp16x2 __attribute__((ext_vector_type(2)));
typedef float f32x4 __attribute__((ext_vector_type(4)));

#define S_LEN 2048
#define D_DIM 64
#define SD (S_LEN * D_DIM)
#define BC 64
#define NKT (S_LEN / BC)   // 32 key tiles
#define LDK 72             // f16 row stride (64 + 8 pad)
#define LDO 68             // f32 row stride for epilogue
#define THR 4.0f           // lazy-max threshold: stale-path P <= 2^4

// 256 threads = 4 waves; wave w owns q rows [32w,32w+32) as two 16-q groups
// (K/V LDS fragments read ONCE per wave-iter, reused by both groups — round 0
// proved this beats 2x occupancy). P never touches LDS (round 2): the
// 16x16x32 QK output is exactly the B-frag of 16x16x16f16 PV MFMAs.
// NEW this round — the common-path iteration has ZERO cross-lane ops:
//  * lazy running max: mrun kept stale; per-lane local max + one wave-uniform
//    __all() test. Online softmax is exact for ANY m (alpha-rescale heals);
//    staleness is bounded by THR so f16 P never overflows (P <= 16).
//    The exact 2-shfl reduce runs only when the bound trips (~once per row).
//  * l-sum via ones-MFMA: accl = mfma(1, P, accl) row-sums P on the matrix
//    pipe (A==1 makes the layout irrelevant; result replicated over rows),
//    removing the lt adds + 2 shfls from the serial VALU chain.
//  * s_setprio(1) around MFMA clusters (T5).
// Rationale: rounds 0-2 showed VALU 41% / LDS ~30% / MFMA 23% — no pipe
// saturated; the wall is the serial softmax chain + barrier convoy.
__global__ __launch_bounds__(256, 2)
void fattn_kernel(const float* __restrict__ Qg, const float* __restrict__ Kg,
                  const float* __restrict__ Vg, const int* __restrict__ Mg,
                  float* __restrict__ Og) {
  __shared__ __align__(16) char smem[45056];
  // K buf0 [0,9216) K buf1 [9216,18432) V buf0 [18432,27648) V buf1 [27648,36864)
  float* Msh = (float*)(smem + 36864);  // [2048] additive mask {0,-1e30}
  float* Osh = (float*)smem;            // [128][68] f32, epilogue reuse

  const int t = threadIdx.x;
  const int w = t >> 6;
  const int lane = t & 63;
  const int g = lane >> 4;   // quad
  const int c = lane & 15;

  // bh in low bits: all 16 q-blocks of one (b,h) hit the SAME XCD
  const int bh = blockIdx.x & 31;
  const int qt = blockIdx.x >> 5;
  const int qb = qt * 128;

  const float* Qb = Qg + (size_t)bh * SD;
  const float* Kb = Kg + (size_t)bh * SD;
  const float* Vb = Vg + (size_t)bh * SD;
  const int*   Mb = Mg + (size_t)(bh >> 3) * S_LEN;  // H = 8
  float*       Ob = Og + (size_t)bh * SD;

  // ---- stage additive mask -> LDS once: (m-1)*1e30 -> {0, -1e30} ----
  {
    int4 m0 = *(const int4*)(Mb + 8 * t);
    int4 m1 = *(const int4*)(Mb + 8 * t + 4);
    float4 f0, f1;
    f0.x = (float)(m0.x - 1) * 1e30f; f0.y = (float)(m0.y - 1) * 1e30f;
    f0.z = (float)(m0.z - 1) * 1e30f; f0.w = (float)(m0.w - 1) * 1e30f;
    f1.x = (float)(m1.x - 1) * 1e30f; f1.y = (float)(m1.y - 1) * 1e30f;
    f1.z = (float)(m1.z - 1) * 1e30f; f1.w = (float)(m1.w - 1) * 1e30f;
    *(float4*)(Msh + 8 * t) = f0;
    *(float4*)(Msh + 8 * t + 4) = f1;
  }

  // ---- Q^T B-frags for q = qb + 32w + 16h + c; fold 1/8 * log2(e) ----
  const float qscale = 0.125f * 1.44269504088896340736f;
  half8_t qf[2][2];
#pragma unroll
  for (int h = 0; h < 2; ++h) {
    const float* qp = Qb + (size_t)(qb + 32 * w + 16 * h + c) * D_DIM + 8 * g;
#pragma unroll
    for (int ks = 0; ks < 2; ++ks) {
      float4 lo = *(const float4*)(qp + 32 * ks);
      float4 hi = *(const float4*)(qp + 32 * ks + 4);
      fp16x2 p0 = __builtin_amdgcn_cvt_pkrtz(lo.x * qscale, lo.y * qscale);
      fp16x2 p1 = __builtin_amdgcn_cvt_pkrtz(lo.z * qscale, lo.w * qscale);
      fp16x2 p2 = __builtin_amdgcn_cvt_pkrtz(hi.x * qscale, hi.y * qscale);
      fp16x2 p3 = __builtin_amdgcn_cvt_pkrtz(hi.z * qscale, hi.w * qscale);
      half8_t hh;
      hh[0] = (_Float16)p0[0]; hh[1] = (_Float16)p0[1];
      hh[2] = (_Float16)p1[0]; hh[3] = (_Float16)p1[1];
      hh[4] = (_Float16)p2[0]; hh[5] = (_Float16)p2[1];
      hh[6] = (_Float16)p3[0]; hh[7] = (_Float16)p3[1];
      qf[h][ks] = hh;
    }
  }

  // ---- staging coordinates (256 threads) ----
  const int krow0 = t >> 4;   // 0..15; K row = krow0 + 16*it
  const int kc4   = t & 15;   // K float4 column
  const int vp    = t >> 3;   // V d-pair 0..31
  const int vkpl  = t & 7;    // V key-pair low; kp = vkpl + 8*kc

  float4 kr[4];
  float2 vr[8];
  auto prefetch = [&](int kb2) {
#pragma unroll
    for (int it = 0; it < 4; ++it)
      kr[it] = *(const float4*)(Kb + (size_t)(kb2 + krow0 + 16 * it) * D_DIM + kc4 * 4);
#pragma unroll
    for (int kc = 0; kc < 4; ++kc) {
      const float* vpp = Vb + (size_t)(kb2 + 2 * (vkpl + 8 * kc)) * D_DIM + 2 * vp;
      vr[2 * kc]     = *(const float2*)(vpp);
      vr[2 * kc + 1] = *(const float2*)(vpp + D_DIM);
    }
  };
  auto stage = [&](int buf) {
    _Float16* Kd = (_Float16*)(smem + 9216 * buf);
    _Float16* Vd = (_Float16*)(smem + 18432 + 9216 * buf);
#pragma unroll
    for (int it = 0; it < 4; ++it) {
      fp16x2 a  = __builtin_amdgcn_cvt_pkrtz(kr[it].x, kr[it].y);
      fp16x2 b2 = __builtin_amdgcn_cvt_pkrtz(kr[it].z, kr[it].w);
      half4_t h;
      h[0] = (_Float16)a[0]; h[1] = (_Float16)a[1];
      h[2] = (_Float16)b2[0]; h[3] = (_Float16)b2[1];
      *(half4_t*)(Kd + (krow0 + 16 * it) * LDK + kc4 * 4) = h;
    }
#pragma unroll
    for (int kc = 0; kc < 4; ++kc) {
      int kp = vkpl + 8 * kc;
      fp16x2 h0 = __builtin_amdgcn_cvt_pkrtz(vr[2 * kc].x, vr[2 * kc + 1].x);
      fp16x2 h1 = __builtin_amdgcn_cvt_pkrtz(vr[2 * kc].y, vr[2 * kc + 1].y);
      half2_t g0; g0[0] = (_Float16)h0[0]; g0[1] = (_Float16)h0[1];
      half2_t g1; g1[0] = (_Float16)h1[0]; g1[1] = (_Float16)h1[1];
      *(half2_t*)(Vd + (2 * vp) * LDK + 2 * kp) = g0;
      *(half2_t*)(Vd + (2 * vp + 1) * LDK + 2 * kp) = g1;
    }
  };

  f32x4 acc[2][4];
  f32x4 accl[2];
#pragma unroll
  for (int h = 0; h < 2; ++h) {
#pragma unroll
    for (int j = 0; j < 4; ++j) accl[h][j] = 0.f;
#pragma unroll
    for (int i = 0; i < 4; ++i)
#pragma unroll
      for (int j = 0; j < 4; ++j) acc[h][i][j] = 0.f;
  }
  float mrun[2] = {-1e30f, -1e30f};

  half4_t ones4;
  ones4[0] = (_Float16)1.0f; ones4[1] = (_Float16)1.0f;
  ones4[2] = (_Float16)1.0f; ones4[3] = (_Float16)1.0f;

  // prologue: tile0 -> buf0; tile1 in flight
  prefetch(0);
  stage(0);
  prefetch(BC);
  __syncthreads();

  for (int kt = 0; kt < NKT; ++kt) {
    const int kb = kt * BC;
    const int cur = kt & 1;

    if (kt < NKT - 1) stage(cur ^ 1);
    if (kt < NKT - 2) prefetch(kb + 2 * BC);

    const _Float16* Kc = (const _Float16*)(smem + 9216 * cur);
    const _Float16* Vc = (const _Float16*)(smem + 18432 + 9216 * cur);

    // ---- S^T = K . Q^T for both q-groups; K frag read ONCE ----
    f32x4 sT[2][4];
    __builtin_amdgcn_s_setprio(1);
#pragma unroll
    for (int mt = 0; mt < 4; ++mt) {
      f32x4 z0, z1;
#pragma unroll
      for (int j = 0; j < 4; ++j) { z0[j] = 0.f; z1[j] = 0.f; }
#pragma unroll
      for (int ks = 0; ks < 2; ++ks) {
        half8_t kf = *(half8_t*)(Kc + (16 * mt + c) * LDK + ks * 32 + 8 * g);
        z0 = __builtin_amdgcn_mfma_f32_16x16x32_f16(kf, qf[0][ks], z0, 0, 0, 0);
        z1 = __builtin_amdgcn_mfma_f32_16x16x32_f16(kf, qf[1][ks], z1, 0, 0, 0);
      }
      sT[0][mt] = z0;
      sT[1][mt] = z1;
    }
    __builtin_amdgcn_s_setprio(0);

    // ---- V A-frags (K=16 PV), shared by both groups; issued early so the
    //      LDS latency hides under the softmax VALU phase ----
    half4_t vf[4][4];  // [d-tile][k-step]
#pragma unroll
    for (int dt = 0; dt < 4; ++dt)
#pragma unroll
      for (int kst = 0; kst < 4; ++kst)
        vf[dt][kst] = *(half4_t*)(Vc + (16 * dt + c) * LDK + 16 * kst + 4 * g);

    // ---- additive mask (broadcast LDS reads), shared by both groups ----
    f32x4 mvf[4];
#pragma unroll
    for (int mt = 0; mt < 4; ++mt)
      mvf[mt] = *(const f32x4*)(Msh + kb + 16 * mt + 4 * g);
#pragma unroll
    for (int h = 0; h < 2; ++h)
#pragma unroll
      for (int mt = 0; mt < 4; ++mt)
#pragma unroll
        for (int r = 0; r < 4; ++r) sT[h][mt][r] += mvf[mt][r];

    // ---- lazy max: per-lane local max only, no cross-lane in common path ----
    float tl[2];
#pragma unroll
    for (int h = 0; h < 2; ++h) {
      float tm0 = fmaxf(fmaxf(sT[h][0][0], sT[h][0][1]),
                        fmaxf(sT[h][0][2], sT[h][0][3]));
      float tm1 = fmaxf(fmaxf(sT[h][1][0], sT[h][1][1]),
                        fmaxf(sT[h][1][2], sT[h][1][3]));
      float tm2 = fmaxf(fmaxf(sT[h][2][0], sT[h][2][1]),
                        fmaxf(sT[h][2][2], sT[h][2][3]));
      float tm3 = fmaxf(fmaxf(sT[h][3][0], sT[h][3][1]),
                        fmaxf(sT[h][3][2], sT[h][3][3]));
      tl[h] = fmaxf(fmaxf(tm0, tm1), fmaxf(tm2, tm3));
    }
    int ok0 = __all(tl[0] <= mrun[0] + THR);
    int ok1 = __all(tl[1] <= mrun[1] + THR);
    if (!(ok0 & ok1)) {
      // rare: exact row-max update + alpha rescale (wave-uniform branch)
#pragma unroll
      for (int h = 0; h < 2; ++h) {
        float tmax = tl[h];
        tmax = fmaxf(tmax, __shfl_xor(tmax, 16));
        tmax = fmaxf(tmax, __shfl_xor(tmax, 32));
        float mnew = fmaxf(mrun[h], tmax);
        float alpha = __builtin_amdgcn_exp2f(mrun[h] - mnew);
        mrun[h] = mnew;
        accl[h][0] *= alpha; accl[h][1] *= alpha;
        accl[h][2] *= alpha; accl[h][3] *= alpha;
#pragma unroll
        for (int mt = 0; mt < 4; ++mt) {
          acc[h][mt][0] *= alpha; acc[h][mt][1] *= alpha;
          acc[h][mt][2] *= alpha; acc[h][mt][3] *= alpha;
        }
      }
    }

    // ---- exp + in-register pack + PV; l-sum folded into a ones-MFMA ----
    __builtin_amdgcn_s_setprio(1);
#pragma unroll
    for (int h = 0; h < 2; ++h) {
#pragma unroll
      for (int mt = 0; mt < 4; ++mt) {
        float pv0 = __builtin_amdgcn_exp2f(sT[h][mt][0] - mrun[h]);
        float pv1 = __builtin_amdgcn_exp2f(sT[h][mt][1] - mrun[h]);
        float pv2 = __builtin_amdgcn_exp2f(sT[h][mt][2] - mrun[h]);
        float pv3 = __builtin_amdgcn_exp2f(sT[h][mt][3] - mrun[h]);
        fp16x2 p01 = __builtin_amdgcn_cvt_pkrtz(pv0, pv1);
        fp16x2 p23 = __builtin_amdgcn_cvt_pkrtz(pv2, pv3);
        half4_t pf;
        pf[0] = (_Float16)p01[0]; pf[1] = (_Float16)p01[1];
        pf[2] = (_Float16)p23[0]; pf[3] = (_Float16)p23[1];
        accl[h] = __builtin_amdgcn_mfma_f32_16x16x16f16(ones4, pf, accl[h], 0, 0, 0);
#pragma unroll
        for (int dt = 0; dt < 4; ++dt)
          acc[h][dt] = __builtin_amdgcn_mfma_f32_16x16x16f16(vf[dt][mt], pf,
                                                             acc[h][dt], 0, 0, 0);
      }
    }
    __builtin_amdgcn_s_setprio(0);

    __syncthreads();  // single barrier: guards next iter's buffer swap
  }

  // ---- epilogue: /l, transpose O^T -> O via LDS, coalesced stores ----
#pragma unroll
  for (int h = 0; h < 2; ++h) {
    float linv = 1.f / accl[h][0];  // ones-MFMA replicates l over rows
#pragma unroll
    for (int mt = 0; mt < 4; ++mt)
#pragma unroll
      for (int r = 0; r < 4; ++r)
        Osh[(32 * w + 16 * h + c) * LDO + 16 * mt + 4 * g + r] = acc[h][mt][r] * linv;
  }
  __syncthreads();
  {
    int f8 = t & 7;
#pragma unroll
    for (int i = 0; i < 4; ++i) {
      int q = (t >> 3) + 32 * i;
#pragma unroll
      for (int j = 0; j < 2; ++j) {
        int c4 = f8 + 8 * j;
        f32x4 o = *(f32x4*)(Osh + q * LDO + c4 * 4);
        *(float4*)(Ob + (size_t)(qb + q) * D_DIM + c4 * 4) =
            make_float4(o.x, o.y, o.z, o.w);
      }
    }
  }
}

extern "C" void kernel_launch(void* const* d_in, const int* in_sizes, int n_in,
                              void* d_out, int out_size, void* d_ws, size_t ws_size,
                              hipStream_t stream) {
  (void)in_sizes; (void)n_in; (void)d_ws; (void)ws_size; (void)out_size;
  const float* Q = (const float*)d_in[0];
  const float* K = (const float*)d_in[1];
  const float* V = (const float*)d_in[2];
  const int*   M = (const int*)d_in[3];
  float* O = (float*)d_out;
  // grid: bh fast (XCD locality), 16 q-tiles slow
  fattn_kernel<<<dim3(32 * 16), dim3(256), 0, stream>>>(Q, K, V, M, O);
}